// Round 1
// 869.622 us; speedup vs baseline: 1.1438x; 1.1438x over previous
//
#include <hip/hip_runtime.h>
#include <math.h>
#include <stdint.h>

// Problem dims (fixed by reference)
static constexpr int Bb  = 4;
static constexpr int Ll  = 4096;
static constexpr int Dd  = 1024;
static constexpr int DFF = 4096;
static constexpr int Mm  = Bb * Ll;     // 16384 rows
static constexpr int CH  = 64;          // scan chunks
static constexpr int CS  = Ll / CH;     // 64 steps per chunk
static constexpr float EPS = 1e-6f;

typedef __attribute__((ext_vector_type(8))) short short8;     // 8 bf16 (4 VGPRs)
typedef __attribute__((ext_vector_type(4))) float floatx4;    // MFMA C/D
typedef __attribute__((ext_vector_type(4))) unsigned short us4;

__device__ __forceinline__ float sigmoidf_(float v) { return 1.0f / (1.0f + __expf(-v)); }
// safe at +-inf: 2*sigmoid(2x)-1
__device__ __forceinline__ float fast_tanh(float x) {
    return 2.0f / (1.0f + __expf(-2.0f * x)) - 1.0f;
}
__device__ __forceinline__ ushort f2bf(float f) {
    union { float f; uint32_t u; } v; v.f = f;
    return (ushort)((v.u + 0x7FFFu + ((v.u >> 16) & 1u)) >> 16);   // RNE
}
__device__ __forceinline__ float bf2f(ushort h) {
    union { uint32_t u; float f; } v; v.u = (uint32_t)h << 16; return v.f;
}

// async global->LDS, 16 bytes per lane (wave-uniform base + lane*16 layout)
__device__ __forceinline__ void gload16(const ushort* g, ushort* l) {
    __builtin_amdgcn_global_load_lds(
        (const __attribute__((address_space(1))) uint32_t*)g,
        (__attribute__((address_space(3))) uint32_t*)l, 16, 0, 0);
}

// ===========================================================================
// 512-thread (8-wave) 256-wide pipelined GEMM core, K-tiles of 32.
//   LDS: 3 buffers x (A[256x32] + Bconcat[256x32]) bf16 = 96 KB
//   B-concat rows [0,128) = B1 rows n0b1..   rows [128,256) = B2 rows n0b2..
//   Swizzle (proven, 0 bank conflicts): chunk c (m=c>>2, s=c&3) holds global
//   k-block kb = s ^ ((m>>1)&3); fragment read slot = q ^ ((r>>1)&3).
//   Schedule per iter t: issue stage(t+2) -> reads buf[t%3] -> 32 MFMA
//   (setprio) -> s_waitcnt vmcnt(4) lgkmcnt(0) -> s_barrier.
//   vmcnt never drains to 0 in the main loop (T4); prefetch depth 2.
//   Race-free: staged buffer was last read 2 barriers ago (reads complete
//   before each barrier via lgkmcnt(0)); tile t's loads are waited at the
//   end of iter t-1 (vmcnt(4): only t+1's 4 newest may remain in flight).
// ===========================================================================
static constexpr int TILE_US = 256 * 32;        // ushorts per 256x32 tile (16 KB)
static constexpr int BUF_US  = 2 * TILE_US;     // A + B per buffer (32 KB)

__device__ __forceinline__ void gemm_core_512(
    const ushort* __restrict__ A, const ushort* __restrict__ B1,
    const ushort* __restrict__ B2, int m0, int n0b1, int n0b2, int K,
    ushort* lds, floatx4 (&acc1)[8][2], floatx4 (&acc2)[8][2])
{
    const int tid = threadIdx.x;
    const int cm = tid >> 2;                          // 0..127
    const int kb = (tid & 3) ^ ((cm >> 1) & 3);       // swizzled k-slot
    const ushort* pa0 = A  + (size_t)(m0 + cm) * K + kb * 8;
    const ushort* pa1 = pa0 + (size_t)128 * K;
    const ushort* pb0 = B1 + (size_t)(n0b1 + cm) * K + kb * 8;
    const ushort* pb1 = B2 + (size_t)(n0b2 + cm) * K + kb * 8;

    const int wave = tid >> 6, lane = tid & 63;
    const int wr = wave >> 2, wc = wave & 3;          // 2 x 4 wave grid
    const int fr = lane & 15, q = lane >> 4;

    int offA[8], offB[2], offC[2];
    #pragma unroll
    for (int mi = 0; mi < 8; ++mi) {
        int r = wr * 128 + mi * 16 + fr;              // A row 0..255
        offA[mi] = r * 32 + ((q ^ ((r >> 1) & 3)) << 3);
    }
    #pragma unroll
    for (int ni = 0; ni < 2; ++ni) {
        int r1 = wc * 32 + ni * 16 + fr;              // B1 half row
        offB[ni] = r1 * 32 + ((q ^ ((r1 >> 1) & 3)) << 3);
        int r2 = r1 + 128;                            // B2 half row
        offC[ni] = r2 * 32 + ((q ^ ((r2 >> 1) & 3)) << 3);
    }

    const int NT = K >> 5;

    // ---- prologue: stage tiles 0 and 1 into buffers 0,1 ----
    {
        ushort* As0 = lds;
        ushort* Bs0 = lds + TILE_US;
        gload16(pa0, As0 + tid * 8); gload16(pa1, As0 + (tid + 512) * 8);
        gload16(pb0, Bs0 + tid * 8); gload16(pb1, Bs0 + (tid + 512) * 8);
        pa0 += 32; pa1 += 32; pb0 += 32; pb1 += 32;
        ushort* As1 = lds + BUF_US;
        ushort* Bs1 = As1 + TILE_US;
        gload16(pa0, As1 + tid * 8); gload16(pa1, As1 + (tid + 512) * 8);
        gload16(pb0, Bs1 + tid * 8); gload16(pb1, Bs1 + (tid + 512) * 8);
        pa0 += 32; pa1 += 32; pb0 += 32; pb1 += 32;
        asm volatile("s_waitcnt vmcnt(4)" ::: "memory");   // tile 0 landed
        __builtin_amdgcn_s_barrier();
    }

    int cur = 0;
    for (int t = 0; t < NT; ++t) {
        // 1) issue prefetch of tile t+2 into buf (cur+2)%3 (read last at t-1)
        if (t + 2 < NT) {
            int nxt2 = cur + 2; if (nxt2 >= 3) nxt2 -= 3;
            ushort* As2 = lds + nxt2 * BUF_US;
            ushort* Bs2 = As2 + TILE_US;
            gload16(pa0, As2 + tid * 8); gload16(pa1, As2 + (tid + 512) * 8);
            gload16(pb0, Bs2 + tid * 8); gload16(pb1, Bs2 + (tid + 512) * 8);
            pa0 += 32; pa1 += 32; pb0 += 32; pb1 += 32;
        }
        // 2) fragment reads for tile t
        const ushort* As = lds + cur * BUF_US;
        const ushort* Bs = As + TILE_US;
        short8 a[8], b[2], c[2];
        #pragma unroll
        for (int mi = 0; mi < 8; ++mi) a[mi] = *(const short8*)&As[offA[mi]];
        #pragma unroll
        for (int ni = 0; ni < 2; ++ni) {
            b[ni] = *(const short8*)&Bs[offB[ni]];
            c[ni] = *(const short8*)&Bs[offC[ni]];
        }
        // 3) MFMA cluster (T5)
        __builtin_amdgcn_s_setprio(1);
        #pragma unroll
        for (int mi = 0; mi < 8; ++mi)
            #pragma unroll
            for (int ni = 0; ni < 2; ++ni) {
                acc1[mi][ni] = __builtin_amdgcn_mfma_f32_16x16x32_bf16(
                    a[mi], b[ni], acc1[mi][ni], 0, 0, 0);
                acc2[mi][ni] = __builtin_amdgcn_mfma_f32_16x16x32_bf16(
                    a[mi], c[ni], acc2[mi][ni], 0, 0, 0);
            }
        __builtin_amdgcn_s_setprio(0);
        // 4) counted wait (never 0 in steady state) + barrier
        if (t + 2 < NT) {
            asm volatile("s_waitcnt vmcnt(4) lgkmcnt(0)" ::: "memory");
        } else {
            asm volatile("s_waitcnt vmcnt(0) lgkmcnt(0)" ::: "memory");
        }
        __builtin_amdgcn_s_barrier();
        cur = (cur + 1 == 3) ? 0 : cur + 1;
    }
}

// ---------------------------------------------------------------------------
// Fused QuasiLSTM gate GEMM (dual, shared A), N = 2048:
//   W1t rows [0,1024) = w_input^T,  [1024,2048) = w_forget^T
//   W2t rows [0,1024) = w_igate^T,  [1024,2048) = w_ogate^T
// col <  1024:  Gb  = tanh(z1) * sigmoid(z2)
// col >= 1024:  Ga  = sigmoid(z1);  Gog = sigmoid(z2)
// ---------------------------------------------------------------------------
__global__ __launch_bounds__(512) void mfma_gemm_gates(
    const ushort* __restrict__ A, const ushort* __restrict__ W1t,
    const ushort* __restrict__ W2t,
    const float* __restrict__ b_input, const float* __restrict__ b_forget,
    const float* __restrict__ b_igate, const float* __restrict__ b_ogate,
    ushort* __restrict__ Ga, ushort* __restrict__ Gb, ushort* __restrict__ Gog)
{
    __shared__ __align__(16) ushort lds[3 * BUF_US];
    constexpr int GXN = 2048 / 128;                  // 16
    const int nwg = (2048 / 128) * (Mm / 256);       // 1024
    int s = (blockIdx.x & 7) * (nwg >> 3) + (blockIdx.x >> 3);   // XCD swizzle
    int bx = s % GXN, by = s / GXN;
    int m0 = by * 256, n0 = bx * 128;

    floatx4 acc1[8][2] = {};
    floatx4 acc2[8][2] = {};
    gemm_core_512(A, W1t, W2t, m0, n0, n0, Dd, lds, acc1, acc2);

    int tid = threadIdx.x, wave = tid >> 6, lane = tid & 63;
    int wr = wave >> 2, wc = wave & 3, fr = lane & 15, q = lane >> 4;
    #pragma unroll
    for (int ni = 0; ni < 2; ++ni) {
        int col = n0 + wc * 32 + ni * 16 + fr;        // [0,2048)
        if (col < 1024) {
            float b1v = b_input[col], b2v = b_igate[col];
            #pragma unroll
            for (int mi = 0; mi < 8; ++mi)
                #pragma unroll
                for (int r = 0; r < 4; ++r) {
                    int row = m0 + wr * 128 + mi * 16 + q * 4 + r;
                    float z1 = acc1[mi][ni][r] + b1v;
                    float z2 = acc2[mi][ni][r] + b2v;
                    Gb[(size_t)row * Dd + col] = f2bf(fast_tanh(z1) * sigmoidf_(z2));
                }
        } else {
            int c2 = col - 1024;
            float b1v = b_forget[c2], b2v = b_ogate[c2];
            #pragma unroll
            for (int mi = 0; mi < 8; ++mi)
                #pragma unroll
                for (int r = 0; r < 4; ++r) {
                    int row = m0 + wr * 128 + mi * 16 + q * 4 + r;
                    float z1 = acc1[mi][ni][r] + b1v;
                    float z2 = acc2[mi][ni][r] + b2v;
                    Ga[(size_t)row * Dd + c2]  = f2bf(sigmoidf_(z1));
                    Gog[(size_t)row * Dd + c2] = f2bf(sigmoidf_(z2));
                }
        }
    }
}

// ---------------------------------------------------------------------------
// MFMA dual GEMM for SwiGLU: C = (A@W1+b1) * silu(A@W2+b2), bf16 out
// ---------------------------------------------------------------------------
__global__ __launch_bounds__(512) void mfma_gemm_swiglu(
    const ushort* __restrict__ A, const ushort* __restrict__ W1t,
    const float* __restrict__ b1, const ushort* __restrict__ W2t,
    const float* __restrict__ b2, ushort* __restrict__ C)
{
    __shared__ __align__(16) ushort lds[3 * BUF_US];
    constexpr int GXN = DFF / 128;                   // 32
    const int nwg = (DFF / 128) * (Mm / 256);        // 2048
    int s = (blockIdx.x & 7) * (nwg >> 3) + (blockIdx.x >> 3);
    int bx = s % GXN, by = s / GXN;
    int m0 = by * 256, n0 = bx * 128;

    floatx4 acc1[8][2] = {};
    floatx4 acc2[8][2] = {};
    gemm_core_512(A, W1t, W2t, m0, n0, n0, Dd, lds, acc1, acc2);

    int tid = threadIdx.x, wave = tid >> 6, lane = tid & 63;
    int wr = wave >> 2, wc = wave & 3, fr = lane & 15, q = lane >> 4;
    #pragma unroll
    for (int ni = 0; ni < 2; ++ni) {
        int col = n0 + wc * 32 + ni * 16 + fr;
        float b1v = b1[col], b2v = b2[col];
        #pragma unroll
        for (int mi = 0; mi < 8; ++mi)
            #pragma unroll
            for (int r = 0; r < 4; ++r) {
                int row = m0 + wr * 128 + mi * 16 + q * 4 + r;
                float z1 = acc1[mi][ni][r] + b1v;
                float z2 = acc2[mi][ni][r] + b2v;
                C[(size_t)row * DFF + col] = f2bf(z1 * z2 * sigmoidf_(z2));
            }
    }
}

// ---------------------------------------------------------------------------
// MFMA residual GEMM: out_f32 = A_bf16[M,K] @ Wt[N,K]^T + bias + R (R == out)
// Single-B: the 256-wide N tile is treated as two 128 halves (acc1/acc2).
// ---------------------------------------------------------------------------
__global__ __launch_bounds__(512) void mfma_gemm_residual(
    const ushort* __restrict__ A, const ushort* __restrict__ Wt,
    const float* __restrict__ bias, float* __restrict__ C)
{
    __shared__ __align__(16) ushort lds[3 * BUF_US];
    constexpr int GXN = Dd / 256;                    // 4
    const int nwg = (Dd / 256) * (Mm / 256);         // 256
    int s = (blockIdx.x & 7) * (nwg >> 3) + (blockIdx.x >> 3);
    int bx = s % GXN, by = s / GXN;
    int m0 = by * 256, n0 = bx * 256;

    floatx4 acc1[8][2] = {};
    floatx4 acc2[8][2] = {};
    gemm_core_512(A, Wt, Wt, m0, n0, n0 + 128, DFF, lds, acc1, acc2);

    int tid = threadIdx.x, wave = tid >> 6, lane = tid & 63;
    int wr = wave >> 2, wc = wave & 3, fr = lane & 15, q = lane >> 4;
    #pragma unroll
    for (int ni = 0; ni < 2; ++ni) {
        int col1 = n0 + wc * 32 + ni * 16 + fr;
        int col2 = col1 + 128;
        float bs1 = bias[col1], bs2 = bias[col2];
        #pragma unroll
        for (int mi = 0; mi < 8; ++mi)
            #pragma unroll
            for (int r = 0; r < 4; ++r) {
                int row = m0 + wr * 128 + mi * 16 + q * 4 + r;
                size_t i1 = (size_t)row * Dd + col1;
                size_t i2 = (size_t)row * Dd + col2;
                C[i1] = acc1[mi][ni][r] + bs1 + C[i1];  // same-thread RMW
                C[i2] = acc2[mi][ni][r] + bs2 + C[i2];
            }
    }
}

// ---------------------------------------------------------------------------
// Weight cast+transpose: W fp32 [K,N] -> Wt bf16 [N,K]
// ---------------------------------------------------------------------------
__global__ __launch_bounds__(256) void transpose_cast_kernel(
    const float* __restrict__ W, ushort* __restrict__ Wt, int K, int N)
{
    __shared__ float t[32][33];
    int lx = threadIdx.x & 31, ly = threadIdx.x >> 5;   // 32 x 8
    int n = blockIdx.x * 32 + lx;
    #pragma unroll
    for (int i = 0; i < 4; ++i) {
        int k = blockIdx.y * 32 + ly + i * 8;
        t[ly + i * 8][lx] = W[(size_t)k * N + n];
    }
    __syncthreads();
    int k2 = blockIdx.y * 32 + lx;
    #pragma unroll
    for (int i = 0; i < 4; ++i) {
        int n2 = blockIdx.x * 32 + ly + i * 8;
        Wt[(size_t)n2 * K + k2] = f2bf(t[lx][ly + i * 8]);
    }
}

// Batched version for the four 1024x1024 gate weights (grid.z picks source).
__global__ __launch_bounds__(256) void transpose_cast_gates(
    const float* __restrict__ w_i, const float* __restrict__ w_f,
    const float* __restrict__ w_g, const float* __restrict__ w_o,
    ushort* __restrict__ W1t, ushort* __restrict__ W2t)
{
    int z = blockIdx.z;
    const float* W = (z == 0) ? w_i : (z == 1) ? w_f : (z == 2) ? w_g : w_o;
    ushort* Wt = (z == 0) ? W1t : (z == 1) ? W1t + (size_t)1024 * Dd
               : (z == 2) ? W2t : W2t + (size_t)1024 * Dd;
    __shared__ float t[32][33];
    int lx = threadIdx.x & 31, ly = threadIdx.x >> 5;
    int n = blockIdx.x * 32 + lx;
    #pragma unroll
    for (int i = 0; i < 4; ++i) {
        int k = blockIdx.y * 32 + ly + i * 8;
        t[ly + i * 8][lx] = W[(size_t)k * Dd + n];
    }
    __syncthreads();
    int k2 = blockIdx.y * 32 + lx;
    #pragma unroll
    for (int i = 0; i < 4; ++i) {
        int n2 = blockIdx.x * 32 + ly + i * 8;
        Wt[(size_t)n2 * Dd + k2] = f2bf(t[lx][ly + i * 8]);
    }
}

// ---------------------------------------------------------------------------
// RMSNorm fp32 in -> bf16 out. One block per row.
// ---------------------------------------------------------------------------
__global__ __launch_bounds__(256) void rmsnorm_bf16_kernel(
    const float* __restrict__ x, const float* __restrict__ w,
    ushort* __restrict__ o)
{
    int row = blockIdx.x;
    int tid = threadIdx.x;
    float4 v = ((const float4*)(x + (size_t)row * Dd))[tid];
    float ss = v.x*v.x + v.y*v.y + v.z*v.z + v.w*v.w;
    #pragma unroll
    for (int off = 32; off > 0; off >>= 1) ss += __shfl_down(ss, off, 64);
    __shared__ float red[4];
    if ((tid & 63) == 0) red[tid >> 6] = ss;
    __syncthreads();
    float scale = rsqrtf((red[0] + red[1] + red[2] + red[3]) * (1.0f / Dd) + EPS);
    float4 wv = ((const float4*)w)[tid];
    us4 ov;
    ov.x = f2bf(v.x * scale * wv.x);
    ov.y = f2bf(v.y * scale * wv.y);
    ov.z = f2bf(v.z * scale * wv.z);
    ov.w = f2bf(v.w * scale * wv.w);
    *(us4*)&o[(size_t)row * Dd + tid * 4] = ov;
}

// ---------------------------------------------------------------------------
// Chunked linear recurrence, 4 channels/thread (ushort4 loads)
// ---------------------------------------------------------------------------
__global__ __launch_bounds__(256) void scan_pass1(
    const ushort* __restrict__ Ga, const ushort* __restrict__ Gb,
    float* __restrict__ P, float* __restrict__ Hend)
{
    int tid = threadIdx.x;
    int c = blockIdx.x, b = blockIdx.y;
    size_t base = ((size_t)b * Ll + (size_t)c * CS) * Dd + tid * 4;
    float p[4] = {1.f, 1.f, 1.f, 1.f};
    float h[4] = {};
    #pragma unroll 4
    for (int t = 0; t < CS; ++t) {
        us4 av = *(const us4*)&Ga[base + (size_t)t * Dd];
        us4 bv = *(const us4*)&Gb[base + (size_t)t * Dd];
        #pragma unroll
        for (int j = 0; j < 4; ++j) {
            float aa = bf2f(av[j]);
            float bb = bf2f(bv[j]);
            p[j] *= aa;
            h[j] = aa * h[j] + bb;
        }
    }
    size_t o = ((size_t)b * CH + c) * Dd + tid * 4;
    *(float4*)&P[o]    = make_float4(p[0], p[1], p[2], p[3]);
    *(float4*)&Hend[o] = make_float4(h[0], h[1], h[2], h[3]);
}

__global__ __launch_bounds__(256) void scan_pass2(
    const float* __restrict__ P, const float* __restrict__ Hend,
    const float* __restrict__ h0, float* __restrict__ Carry)
{
    int idx = blockIdx.x * 256 + threadIdx.x;  // B*D = 4096
    int b = idx / Dd, d = idx % Dd;
    float carry = h0[d];
    for (int c = 0; c < CH; ++c) {
        size_t o = ((size_t)b * CH + c) * Dd + d;
        Carry[o] = carry;
        carry = P[o] * carry + Hend[o];
    }
}

// Replay with carry + fused ogate/residual + fused RMSNorm2
__global__ __launch_bounds__(256) void scan_pass3_norm(
    const ushort* __restrict__ Ga, const ushort* __restrict__ Gb,
    const ushort* __restrict__ Gog, const float* __restrict__ Carry,
    const float* __restrict__ x, const float* __restrict__ norm2w,
    float* __restrict__ x1, ushort* __restrict__ xnb)
{
    int tid = threadIdx.x;
    int c = blockIdx.x, b = blockIdx.y;
    size_t base = ((size_t)b * Ll + (size_t)c * CS) * Dd + tid * 4;
    float4 h4 = *(const float4*)&Carry[((size_t)b * CH + c) * Dd + tid * 4];
    float h[4] = {h4.x, h4.y, h4.z, h4.w};
    float4 w4 = ((const float4*)norm2w)[tid];
    float wv[4] = {w4.x, w4.y, w4.z, w4.w};
    __shared__ float red[4];

    for (int t = 0; t < CS; ++t) {
        size_t i = base + (size_t)t * Dd;
        us4 av = *(const us4*)&Ga[i];
        us4 bv = *(const us4*)&Gb[i];
        us4 gv = *(const us4*)&Gog[i];
        float4 xv = *(const float4*)&x[i];
        float xs[4] = {xv.x, xv.y, xv.z, xv.w};
        float v[4];
        #pragma unroll
        for (int j = 0; j < 4; ++j) {
            float aa = bf2f(av[j]);
            float bb = bf2f(bv[j]);
            h[j] = aa * h[j] + bb;
            v[j] = fast_tanh(h[j]) * bf2f(gv[j]) + xs[j];
        }
        *(float4*)&x1[i] = make_float4(v[0], v[1], v[2], v[3]);
        float ss = v[0]*v[0] + v[1]*v[1] + v[2]*v[2] + v[3]*v[3];
        #pragma unroll
        for (int off = 32; off > 0; off >>= 1) ss += __shfl_down(ss, off, 64);
        if ((tid & 63) == 0) red[tid >> 6] = ss;
        __syncthreads();
        float scale = rsqrtf((red[0] + red[1] + red[2] + red[3]) * (1.0f / Dd) + EPS);
        us4 ov;
        #pragma unroll
        for (int j = 0; j < 4; ++j) ov[j] = f2bf(v[j] * scale * wv[j]);
        *(us4*)&xnb[i] = ov;
        __syncthreads();   // protect red[] before next t overwrites
    }
}

// ---------------------------------------------------------------------------
// Launch. Workspace (195 MB):
//   [0,4)   MB: W1t gates bf16 [2048,1024]   (input | forget)
//   [4,8)   MB: W2t gates bf16 [2048,1024]   (igate | ogate)
//   [8,16)  MB: wtFC   [16,24) MB: wtFCA   [24,32) MB: wtOUT
//   [32,64) MB: xnb bf16 [M,1024]
//   [64,192)MB: Ga/Gb/Gog bf16 (32MB each) -> later hff bf16 [M,4096]
//   [192,195)MB: P, Hend, Carry fp32
// d_out doubles as x1 then final out.
// ---------------------------------------------------------------------------
extern "C" void kernel_launch(void* const* d_in, const int* in_sizes, int n_in,
                              void* d_out, int out_size, void* d_ws, size_t ws_size,
                              hipStream_t stream)
{
    const float* x        = (const float*)d_in[0];
    const float* w_forget = (const float*)d_in[1];
    const float* b_forget = (const float*)d_in[2];
    const float* w_input  = (const float*)d_in[3];
    const float* b_input  = (const float*)d_in[4];
    const float* w_igate  = (const float*)d_in[5];
    const float* b_igate  = (const float*)d_in[6];
    const float* w_ogate  = (const float*)d_in[7];
    const float* b_ogate  = (const float*)d_in[8];
    const float* h0       = (const float*)d_in[9];
    const float* norm1_w  = (const float*)d_in[10];
    const float* norm2_w  = (const float*)d_in[11];
    const float* w_fc     = (const float*)d_in[12];
    const float* b_fc     = (const float*)d_in[13];
    const float* w_fc_act = (const float*)d_in[14];
    const float* b_fc_act = (const float*)d_in[15];
    const float* w_out    = (const float*)d_in[16];
    const float* b_out    = (const float*)d_in[17];
    float* out = (float*)d_out;   // x1, then final out

    char* ws = (char*)d_ws;
    const size_t MB = 1ull << 20;
    ushort* wtG1  = (ushort*)(ws + 0 * MB);
    ushort* wtG2  = (ushort*)(ws + 4 * MB);
    ushort* wtFC  = (ushort*)(ws + 8 * MB);
    ushort* wtFCA = (ushort*)(ws + 16 * MB);
    ushort* wtOUT = (ushort*)(ws + 24 * MB);
    ushort* xnb   = (ushort*)(ws + 32 * MB);
    ushort* Ga    = (ushort*)(ws + 64 * MB);
    ushort* Gb    = (ushort*)(ws + 96 * MB);
    ushort* Gog   = (ushort*)(ws + 128 * MB);
    ushort* hff   = (ushort*)(ws + 64 * MB);   // [M,4096] bf16, reuses gate region
    float*  P     = (float*)(ws + 192 * MB);
    float*  Hend  = (float*)(ws + 193 * MB);
    float*  Carry = (float*)(ws + 194 * MB);

    // 0) weights -> bf16 [N,K]
    transpose_cast_gates<<<dim3(32, 32, 4), 256, 0, stream>>>(
        w_input, w_forget, w_igate, w_ogate, wtG1, wtG2);
    transpose_cast_kernel<<<dim3(DFF/32, Dd/32), 256, 0, stream>>>(w_fc,     wtFC,  Dd, DFF);
    transpose_cast_kernel<<<dim3(DFF/32, Dd/32), 256, 0, stream>>>(w_fc_act, wtFCA, Dd, DFF);
    transpose_cast_kernel<<<dim3(Dd/32, DFF/32), 256, 0, stream>>>(w_out,    wtOUT, DFF, Dd);

    // 1) xn = rmsnorm(x) -> bf16
    rmsnorm_bf16_kernel<<<Mm, 256, 0, stream>>>(x, norm1_w, xnb);

    // 2) all four gates in one dual-GEMM (N = 2048), 256x128 tiles, pipelined
    mfma_gemm_gates<<<(2048/128) * (Mm/256), 512, 0, stream>>>(
        xnb, wtG1, wtG2, b_input, b_forget, b_igate, b_ogate, Ga, Gb, Gog);

    // 3) chunked scan + fused ogate/residual + fused rmsnorm2
    dim3 sg(CH, Bb);
    scan_pass1<<<sg, 256, 0, stream>>>(Ga, Gb, P, Hend);
    scan_pass2<<<(Bb * Dd) / 256, 256, 0, stream>>>(P, Hend, h0, Carry);
    scan_pass3_norm<<<sg, 256, 0, stream>>>(Ga, Gb, Gog, Carry, x, norm2_w,
                                            out, xnb);

    // 4) hff = (xn2@w_fc + b) * silu(xn2@w_fc_act + b)  -> bf16 [M,4096]
    mfma_gemm_swiglu<<<(DFF/128) * (Mm/256), 512, 0, stream>>>(
        xnb, wtFC, b_fc, wtFCA, b_fc_act, hff);

    // 5) out = hff @ w_out + b_out + x1   (in-place on d_out)
    mfma_gemm_residual<<<(Dd/256) * (Mm/256), 512, 0, stream>>>(
        hff, wtOUT, b_out, out);
}

// Round 2
// 853.791 us; speedup vs baseline: 1.1650x; 1.0185x over previous
//
#include <hip/hip_runtime.h>
#include <math.h>
#include <stdint.h>

// Problem dims (fixed by reference)
static constexpr int Bb  = 4;
static constexpr int Ll  = 4096;
static constexpr int Dd  = 1024;
static constexpr int DFF = 4096;
static constexpr int Mm  = Bb * Ll;     // 16384 rows
static constexpr int CH  = 64;          // scan chunks
static constexpr int CS  = Ll / CH;     // 64 steps per chunk
static constexpr float EPS = 1e-6f;

typedef __attribute__((ext_vector_type(8))) short short8;     // 8 bf16 (4 VGPRs)
typedef __attribute__((ext_vector_type(4))) float floatx4;    // MFMA C/D
typedef __attribute__((ext_vector_type(4))) unsigned short us4;

__device__ __forceinline__ float sigmoidf_(float v) { return 1.0f / (1.0f + __expf(-v)); }
// safe at +-inf: 2*sigmoid(2x)-1
__device__ __forceinline__ float fast_tanh(float x) {
    return 2.0f / (1.0f + __expf(-2.0f * x)) - 1.0f;
}
__device__ __forceinline__ ushort f2bf(float f) {
    union { float f; uint32_t u; } v; v.f = f;
    return (ushort)((v.u + 0x7FFFu + ((v.u >> 16) & 1u)) >> 16);   // RNE
}
__device__ __forceinline__ float bf2f(ushort h) {
    union { uint32_t u; float f; } v; v.u = (uint32_t)h << 16; return v.f;
}

// async global->LDS, 16 bytes per lane (wave-uniform base + lane*16 layout)
__device__ __forceinline__ void gload16(const ushort* g, ushort* l) {
    __builtin_amdgcn_global_load_lds(
        (const __attribute__((address_space(1))) uint32_t*)g,
        (__attribute__((address_space(3))) uint32_t*)l, 16, 0, 0);
}

// ===========================================================================
// 8-phase pipelined dual-GEMM core (m201 template port), 512 thr / 8 waves.
//   Block tile: 256 rows (A) x 128 cols x 2 outputs (B1,B2 share A);
//   B-LDS holds 256 rows = [B1 128 | B2 128].  BK = 64, split kk0/kk1.
//   LDS per buffer = [Akk0|Akk1|Bkk0|Bkk1], each half-tile 256x32 bf16
//   (16 KB contiguous, linear for global_load_lds).  2 buffers = 128 KB.
//   Swizzle (0-conflict proven): chunk (m, s) holds k-block s ^ ((m>>1)&3);
//   read slot = q ^ ((fr>>1)&3)  (independent of mi/ni/wr/wc).
//   Per K-tile: 4 phases {ds_read 8/4 + stage 1 half-tile -> barrier ->
//   setprio(1) 16 MFMA setprio(0) -> [vmcnt(4) on ph1/ph3] -> barrier}.
//   vmcnt never drains to 0 mid-loop (T4).  In-flight invariant: entering
//   K-tile t exactly {A(t,kk1),B(t,kk1)} (4 loads) outstanding; each
//   vmcnt(4) retires exactly the 2 half-tiles the next 2 phases read.
//   Buffer overwrite happens >= 2 barriers after last read; sched_barrier(0)
//   before each closing barrier pins reads/stages inside their phase.
// ===========================================================================
static constexpr int HT_US  = 256 * 32;       // ushorts per half-tile (16 KB)
static constexpr int BUF_US = 4 * HT_US;      // per buffer (64 KB)

__device__ __forceinline__ void gemm_core_8ph(
    const ushort* __restrict__ A, const ushort* __restrict__ B1,
    const ushort* __restrict__ B2, int m0, int n0b1, int n0b2, int K,
    ushort* lds, floatx4 (&acc1)[8][2], floatx4 (&acc2)[8][2])
{
    const int tid = threadIdx.x;
    const int mm = tid >> 2, ss = tid & 3;
    const int kb = ss ^ ((mm >> 1) & 3);          // swizzled k-slot (staging)
    const ushort* pA0 = A  + (size_t)(m0 + mm) * K + kb * 8;
    const ushort* pA1 = pA0 + (size_t)128 * K;
    const ushort* pB0 = B1 + (size_t)(n0b1 + mm) * K + kb * 8;
    const ushort* pB1 = B2 + (size_t)(n0b2 + mm) * K + kb * 8;

    const int wave = tid >> 6, lane = tid & 63;
    const int wr = wave >> 2, wc = wave & 3;      // 2M x 4N wave grid
    const int fr = lane & 15, q = lane >> 4;
    const int slot8 = (q ^ ((fr >> 1) & 3)) << 3;
    const int aoff  = (wr * 128 + fr) * 32 + slot8;             // + mi*512
    const int boff  = 2 * HT_US + (wc * 32 + fr) * 32 + slot8;  // + ni*512 (+4096 side2)

    const int NT = K >> 6;

#define STG_A(bsel, kk, tt) do { \
        ushort* d_ = lds + (bsel) * BUF_US + (kk) * HT_US; \
        int o_ = (tt) * 64 + (kk) * 32; \
        gload16(pA0 + o_, d_ + tid * 8); \
        gload16(pA1 + o_, d_ + (tid + 512) * 8); } while (0)
#define STG_B(bsel, kk, tt) do { \
        ushort* d_ = lds + (bsel) * BUF_US + (2 + (kk)) * HT_US; \
        int o_ = (tt) * 64 + (kk) * 32; \
        gload16(pB0 + o_, d_ + tid * 8); \
        gload16(pB1 + o_, d_ + (tid + 512) * 8); } while (0)
#define MFMA_HALF(mh) do { \
        __builtin_amdgcn_s_setprio(1); \
        _Pragma("unroll") \
        for (int i_ = 0; i_ < 4; ++i_) { \
            acc1[(mh)*4+i_][0] = __builtin_amdgcn_mfma_f32_16x16x32_bf16(a[i_], b[0], acc1[(mh)*4+i_][0], 0, 0, 0); \
            acc2[(mh)*4+i_][0] = __builtin_amdgcn_mfma_f32_16x16x32_bf16(a[i_], c[0], acc2[(mh)*4+i_][0], 0, 0, 0); \
            acc1[(mh)*4+i_][1] = __builtin_amdgcn_mfma_f32_16x16x32_bf16(a[i_], b[1], acc1[(mh)*4+i_][1], 0, 0, 0); \
            acc2[(mh)*4+i_][1] = __builtin_amdgcn_mfma_f32_16x16x32_bf16(a[i_], c[1], acc2[(mh)*4+i_][1], 0, 0, 0); \
        } \
        __builtin_amdgcn_s_setprio(0); } while (0)
#define CLOSE_BAR() do { __builtin_amdgcn_sched_barrier(0); __builtin_amdgcn_s_barrier(); } while (0)

    // ---- prologue: stage K-tile 0; leave its kk1 halves in flight ----
    STG_A(0, 0, 0); STG_B(0, 0, 0); STG_A(0, 1, 0); STG_B(0, 1, 0);
    asm volatile("s_waitcnt vmcnt(4)" ::: "memory");
    CLOSE_BAR();

    for (int t = 0; t < NT; ++t) {
        const int buf = t & 1, nbuf = buf ^ 1;
        const bool pf = (t + 1 < NT);
        const ushort* Ab = lds + buf * BUF_US;
        short8 a[4], b[2], c[2];

        // ---------- phase 0: kk0, rows mh0 (8 ds_read + stage A kk0) ----------
        #pragma unroll
        for (int i = 0; i < 4; ++i) a[i] = *(const short8*)&Ab[aoff + i * 512];
        #pragma unroll
        for (int n = 0; n < 2; ++n) {
            b[n] = *(const short8*)&Ab[boff + n * 512];
            c[n] = *(const short8*)&Ab[boff + 4096 + n * 512];
        }
        if (pf) STG_A(nbuf, 0, t + 1);
        __builtin_amdgcn_s_barrier();
        MFMA_HALF(0);
        CLOSE_BAR();

        // ---------- phase 1: kk0, rows mh1 (4 ds_read + stage B kk0) ----------
        #pragma unroll
        for (int i = 0; i < 4; ++i) a[i] = *(const short8*)&Ab[aoff + (i + 4) * 512];
        if (pf) STG_B(nbuf, 0, t + 1);
        __builtin_amdgcn_s_barrier();
        MFMA_HALF(1);
        if (pf) asm volatile("s_waitcnt vmcnt(4)" ::: "memory");
        else    asm volatile("s_waitcnt vmcnt(0)" ::: "memory");
        CLOSE_BAR();

        // ---------- phase 2: kk1, rows mh0 (8 ds_read + stage A kk1) ----------
        const ushort* Ab1 = Ab + HT_US;
        #pragma unroll
        for (int i = 0; i < 4; ++i) a[i] = *(const short8*)&Ab1[aoff + i * 512];
        #pragma unroll
        for (int n = 0; n < 2; ++n) {
            b[n] = *(const short8*)&Ab1[boff + n * 512];
            c[n] = *(const short8*)&Ab1[boff + 4096 + n * 512];
        }
        if (pf) STG_A(nbuf, 1, t + 1);
        __builtin_amdgcn_s_barrier();
        MFMA_HALF(0);
        CLOSE_BAR();

        // ---------- phase 3: kk1, rows mh1 (4 ds_read + stage B kk1) ----------
        #pragma unroll
        for (int i = 0; i < 4; ++i) a[i] = *(const short8*)&Ab1[aoff + (i + 4) * 512];
        if (pf) STG_B(nbuf, 1, t + 1);
        __builtin_amdgcn_s_barrier();
        MFMA_HALF(1);
        if (pf) asm volatile("s_waitcnt vmcnt(4)" ::: "memory");
        CLOSE_BAR();
    }
#undef STG_A
#undef STG_B
#undef MFMA_HALF
#undef CLOSE_BAR
}

// ---------------------------------------------------------------------------
// Fused QuasiLSTM gate GEMM (dual, shared A), N = 2048:
//   W1t rows [0,1024) = w_input^T,  [1024,2048) = w_forget^T
//   W2t rows [0,1024) = w_igate^T,  [1024,2048) = w_ogate^T
// col <  1024:  Gb  = tanh(z1) * sigmoid(z2)
// col >= 1024:  Ga  = sigmoid(z1);  Gog = sigmoid(z2)
// ---------------------------------------------------------------------------
__global__ __launch_bounds__(512) void mfma_gemm_gates(
    const ushort* __restrict__ A, const ushort* __restrict__ W1t,
    const ushort* __restrict__ W2t,
    const float* __restrict__ b_input, const float* __restrict__ b_forget,
    const float* __restrict__ b_igate, const float* __restrict__ b_ogate,
    ushort* __restrict__ Ga, ushort* __restrict__ Gb, ushort* __restrict__ Gog)
{
    __shared__ __align__(16) ushort lds[2 * BUF_US];
    // XCD-slice swizzle: each XCD owns 2 bx columns (B-slice 1MB, L2-resident)
    int xcd = blockIdx.x & 7, i = blockIdx.x >> 3;   // i in [0,128)
    int bx = xcd * 2 + (i & 1), by = i >> 1;
    int m0 = by * 256, n0 = bx * 128;

    floatx4 acc1[8][2] = {};
    floatx4 acc2[8][2] = {};
    gemm_core_8ph(A, W1t, W2t, m0, n0, n0, Dd, lds, acc1, acc2);

    int tid = threadIdx.x, wave = tid >> 6, lane = tid & 63;
    int wr = wave >> 2, wc = wave & 3, fr = lane & 15, q = lane >> 4;
    #pragma unroll
    for (int ni = 0; ni < 2; ++ni) {
        int col = n0 + wc * 32 + ni * 16 + fr;        // [0,2048)
        if (col < 1024) {
            float b1v = b_input[col], b2v = b_igate[col];
            #pragma unroll
            for (int mi = 0; mi < 8; ++mi)
                #pragma unroll
                for (int r = 0; r < 4; ++r) {
                    int row = m0 + wr * 128 + mi * 16 + q * 4 + r;
                    float z1 = acc1[mi][ni][r] + b1v;
                    float z2 = acc2[mi][ni][r] + b2v;
                    Gb[(size_t)row * Dd + col] = f2bf(fast_tanh(z1) * sigmoidf_(z2));
                }
        } else {
            int c2 = col - 1024;
            float b1v = b_forget[c2], b2v = b_ogate[c2];
            #pragma unroll
            for (int mi = 0; mi < 8; ++mi)
                #pragma unroll
                for (int r = 0; r < 4; ++r) {
                    int row = m0 + wr * 128 + mi * 16 + q * 4 + r;
                    float z1 = acc1[mi][ni][r] + b1v;
                    float z2 = acc2[mi][ni][r] + b2v;
                    Ga[(size_t)row * Dd + c2]  = f2bf(sigmoidf_(z1));
                    Gog[(size_t)row * Dd + c2] = f2bf(sigmoidf_(z2));
                }
        }
    }
}

// ---------------------------------------------------------------------------
// MFMA dual GEMM for SwiGLU: C = (A@W1+b1) * silu(A@W2+b2), bf16 out
// ---------------------------------------------------------------------------
__global__ __launch_bounds__(512) void mfma_gemm_swiglu(
    const ushort* __restrict__ A, const ushort* __restrict__ W1t,
    const float* __restrict__ b1, const ushort* __restrict__ W2t,
    const float* __restrict__ b2, ushort* __restrict__ C)
{
    __shared__ __align__(16) ushort lds[2 * BUF_US];
    // XCD-slice swizzle: each XCD owns 4 bx columns (B-slice 2MB, L2-resident)
    int xcd = blockIdx.x & 7, i = blockIdx.x >> 3;   // i in [0,256)
    int bx = xcd * 4 + (i & 3), by = i >> 2;
    int m0 = by * 256, n0 = bx * 128;

    floatx4 acc1[8][2] = {};
    floatx4 acc2[8][2] = {};
    gemm_core_8ph(A, W1t, W2t, m0, n0, n0, Dd, lds, acc1, acc2);

    int tid = threadIdx.x, wave = tid >> 6, lane = tid & 63;
    int wr = wave >> 2, wc = wave & 3, fr = lane & 15, q = lane >> 4;
    #pragma unroll
    for (int ni = 0; ni < 2; ++ni) {
        int col = n0 + wc * 32 + ni * 16 + fr;
        float b1v = b1[col], b2v = b2[col];
        #pragma unroll
        for (int mi = 0; mi < 8; ++mi)
            #pragma unroll
            for (int r = 0; r < 4; ++r) {
                int row = m0 + wr * 128 + mi * 16 + q * 4 + r;
                float z1 = acc1[mi][ni][r] + b1v;
                float z2 = acc2[mi][ni][r] + b2v;
                C[(size_t)row * DFF + col] = f2bf(z1 * z2 * sigmoidf_(z2));
            }
    }
}

// ---------------------------------------------------------------------------
// MFMA residual GEMM: out_f32 = A_bf16[M,K] @ Wt[N,K]^T + bias + R (R == out)
// Single-B: the 256-wide N tile is two 128 halves (acc1/acc2).
// ---------------------------------------------------------------------------
__global__ __launch_bounds__(512) void mfma_gemm_residual(
    const ushort* __restrict__ A, const ushort* __restrict__ Wt,
    const float* __restrict__ bias, float* __restrict__ C)
{
    __shared__ __align__(16) ushort lds[2 * BUF_US];
    int xcd = blockIdx.x & 7, i = blockIdx.x >> 3;   // i in [0,32)
    int s = xcd * 32 + i;
    int bx = s & 3, by = s >> 2;                     // bx fast: A-panel reuse
    int m0 = by * 256, n0 = bx * 256;

    floatx4 acc1[8][2] = {};
    floatx4 acc2[8][2] = {};
    gemm_core_8ph(A, Wt, Wt, m0, n0, n0 + 128, DFF, lds, acc1, acc2);

    int tid = threadIdx.x, wave = tid >> 6, lane = tid & 63;
    int wr = wave >> 2, wc = wave & 3, fr = lane & 15, q = lane >> 4;
    #pragma unroll
    for (int ni = 0; ni < 2; ++ni) {
        int col1 = n0 + wc * 32 + ni * 16 + fr;
        int col2 = col1 + 128;
        float bs1 = bias[col1], bs2 = bias[col2];
        #pragma unroll
        for (int mi = 0; mi < 8; ++mi)
            #pragma unroll
            for (int r = 0; r < 4; ++r) {
                int row = m0 + wr * 128 + mi * 16 + q * 4 + r;
                size_t i1 = (size_t)row * Dd + col1;
                size_t i2 = (size_t)row * Dd + col2;
                C[i1] = acc1[mi][ni][r] + bs1 + C[i1];  // same-thread RMW
                C[i2] = acc2[mi][ni][r] + bs2 + C[i2];
            }
    }
}

// ---------------------------------------------------------------------------
// Weight cast+transpose: W fp32 [K,N] -> Wt bf16 [N,K]
// ---------------------------------------------------------------------------
__global__ __launch_bounds__(256) void transpose_cast_kernel(
    const float* __restrict__ W, ushort* __restrict__ Wt, int K, int N)
{
    __shared__ float t[32][33];
    int lx = threadIdx.x & 31, ly = threadIdx.x >> 5;   // 32 x 8
    int n = blockIdx.x * 32 + lx;
    #pragma unroll
    for (int i = 0; i < 4; ++i) {
        int k = blockIdx.y * 32 + ly + i * 8;
        t[ly + i * 8][lx] = W[(size_t)k * N + n];
    }
    __syncthreads();
    int k2 = blockIdx.y * 32 + lx;
    #pragma unroll
    for (int i = 0; i < 4; ++i) {
        int n2 = blockIdx.x * 32 + ly + i * 8;
        Wt[(size_t)n2 * K + k2] = f2bf(t[lx][ly + i * 8]);
    }
}

// Batched version for the four 1024x1024 gate weights (grid.z picks source).
__global__ __launch_bounds__(256) void transpose_cast_gates(
    const float* __restrict__ w_i, const float* __restrict__ w_f,
    const float* __restrict__ w_g, const float* __restrict__ w_o,
    ushort* __restrict__ W1t, ushort* __restrict__ W2t)
{
    int z = blockIdx.z;
    const float* W = (z == 0) ? w_i : (z == 1) ? w_f : (z == 2) ? w_g : w_o;
    ushort* Wt = (z == 0) ? W1t : (z == 1) ? W1t + (size_t)1024 * Dd
               : (z == 2) ? W2t : W2t + (size_t)1024 * Dd;
    __shared__ float t[32][33];
    int lx = threadIdx.x & 31, ly = threadIdx.x >> 5;
    int n = blockIdx.x * 32 + lx;
    #pragma unroll
    for (int i = 0; i < 4; ++i) {
        int k = blockIdx.y * 32 + ly + i * 8;
        t[ly + i * 8][lx] = W[(size_t)k * Dd + n];
    }
    __syncthreads();
    int k2 = blockIdx.y * 32 + lx;
    #pragma unroll
    for (int i = 0; i < 4; ++i) {
        int n2 = blockIdx.x * 32 + ly + i * 8;
        Wt[(size_t)n2 * Dd + k2] = f2bf(t[lx][ly + i * 8]);
    }
}

// ---------------------------------------------------------------------------
// RMSNorm fp32 in -> bf16 out. One block per row.
// ---------------------------------------------------------------------------
__global__ __launch_bounds__(256) void rmsnorm_bf16_kernel(
    const float* __restrict__ x, const float* __restrict__ w,
    ushort* __restrict__ o)
{
    int row = blockIdx.x;
    int tid = threadIdx.x;
    float4 v = ((const float4*)(x + (size_t)row * Dd))[tid];
    float ss = v.x*v.x + v.y*v.y + v.z*v.z + v.w*v.w;
    #pragma unroll
    for (int off = 32; off > 0; off >>= 1) ss += __shfl_down(ss, off, 64);
    __shared__ float red[4];
    if ((tid & 63) == 0) red[tid >> 6] = ss;
    __syncthreads();
    float scale = rsqrtf((red[0] + red[1] + red[2] + red[3]) * (1.0f / Dd) + EPS);
    float4 wv = ((const float4*)w)[tid];
    us4 ov;
    ov.x = f2bf(v.x * scale * wv.x);
    ov.y = f2bf(v.y * scale * wv.y);
    ov.z = f2bf(v.z * scale * wv.z);
    ov.w = f2bf(v.w * scale * wv.w);
    *(us4*)&o[(size_t)row * Dd + tid * 4] = ov;
}

// ---------------------------------------------------------------------------
// Chunked linear recurrence, 4 channels/thread (ushort4 loads)
// ---------------------------------------------------------------------------
__global__ __launch_bounds__(256) void scan_pass1(
    const ushort* __restrict__ Ga, const ushort* __restrict__ Gb,
    float* __restrict__ P, float* __restrict__ Hend)
{
    int tid = threadIdx.x;
    int c = blockIdx.x, b = blockIdx.y;
    size_t base = ((size_t)b * Ll + (size_t)c * CS) * Dd + tid * 4;
    float p[4] = {1.f, 1.f, 1.f, 1.f};
    float h[4] = {};
    #pragma unroll 4
    for (int t = 0; t < CS; ++t) {
        us4 av = *(const us4*)&Ga[base + (size_t)t * Dd];
        us4 bv = *(const us4*)&Gb[base + (size_t)t * Dd];
        #pragma unroll
        for (int j = 0; j < 4; ++j) {
            float aa = bf2f(av[j]);
            float bb = bf2f(bv[j]);
            p[j] *= aa;
            h[j] = aa * h[j] + bb;
        }
    }
    size_t o = ((size_t)b * CH + c) * Dd + tid * 4;
    *(float4*)&P[o]    = make_float4(p[0], p[1], p[2], p[3]);
    *(float4*)&Hend[o] = make_float4(h[0], h[1], h[2], h[3]);
}

__global__ __launch_bounds__(256) void scan_pass2(
    const float* __restrict__ P, const float* __restrict__ Hend,
    const float* __restrict__ h0, float* __restrict__ Carry)
{
    int idx = blockIdx.x * 256 + threadIdx.x;  // B*D = 4096
    int b = idx / Dd, d = idx % Dd;
    float carry = h0[d];
    for (int c = 0; c < CH; ++c) {
        size_t o = ((size_t)b * CH + c) * Dd + d;
        Carry[o] = carry;
        carry = P[o] * carry + Hend[o];
    }
}

// Replay with carry + fused ogate/residual + fused RMSNorm2
__global__ __launch_bounds__(256) void scan_pass3_norm(
    const ushort* __restrict__ Ga, const ushort* __restrict__ Gb,
    const ushort* __restrict__ Gog, const float* __restrict__ Carry,
    const float* __restrict__ x, const float* __restrict__ norm2w,
    float* __restrict__ x1, ushort* __restrict__ xnb)
{
    int tid = threadIdx.x;
    int c = blockIdx.x, b = blockIdx.y;
    size_t base = ((size_t)b * Ll + (size_t)c * CS) * Dd + tid * 4;
    float4 h4 = *(const float4*)&Carry[((size_t)b * CH + c) * Dd + tid * 4];
    float h[4] = {h4.x, h4.y, h4.z, h4.w};
    float4 w4 = ((const float4*)norm2w)[tid];
    float wv[4] = {w4.x, w4.y, w4.z, w4.w};
    __shared__ float red[4];

    for (int t = 0; t < CS; ++t) {
        size_t i = base + (size_t)t * Dd;
        us4 av = *(const us4*)&Ga[i];
        us4 bv = *(const us4*)&Gb[i];
        us4 gv = *(const us4*)&Gog[i];
        float4 xv = *(const float4*)&x[i];
        float xs[4] = {xv.x, xv.y, xv.z, xv.w};
        float v[4];
        #pragma unroll
        for (int j = 0; j < 4; ++j) {
            float aa = bf2f(av[j]);
            float bb = bf2f(bv[j]);
            h[j] = aa * h[j] + bb;
            v[j] = fast_tanh(h[j]) * bf2f(gv[j]) + xs[j];
        }
        *(float4*)&x1[i] = make_float4(v[0], v[1], v[2], v[3]);
        float ss = v[0]*v[0] + v[1]*v[1] + v[2]*v[2] + v[3]*v[3];
        #pragma unroll
        for (int off = 32; off > 0; off >>= 1) ss += __shfl_down(ss, off, 64);
        if ((tid & 63) == 0) red[tid >> 6] = ss;
        __syncthreads();
        float scale = rsqrtf((red[0] + red[1] + red[2] + red[3]) * (1.0f / Dd) + EPS);
        us4 ov;
        #pragma unroll
        for (int j = 0; j < 4; ++j) ov[j] = f2bf(v[j] * scale * wv[j]);
        *(us4*)&xnb[i] = ov;
        __syncthreads();   // protect red[] before next t overwrites
    }
}

// ---------------------------------------------------------------------------
// Launch. Workspace (195 MB):
//   [0,4)   MB: W1t gates bf16 [2048,1024]   (input | forget)
//   [4,8)   MB: W2t gates bf16 [2048,1024]   (igate | ogate)
//   [8,16)  MB: wtFC   [16,24) MB: wtFCA   [24,32) MB: wtOUT
//   [32,64) MB: xnb bf16 [M,1024]
//   [64,192)MB: Ga/Gb/Gog bf16 (32MB each) -> later hff bf16 [M,4096]
//   [192,195)MB: P, Hend, Carry fp32
// d_out doubles as x1 then final out.
// ---------------------------------------------------------------------------
extern "C" void kernel_launch(void* const* d_in, const int* in_sizes, int n_in,
                              void* d_out, int out_size, void* d_ws, size_t ws_size,
                              hipStream_t stream)
{
    const float* x        = (const float*)d_in[0];
    const float* w_forget = (const float*)d_in[1];
    const float* b_forget = (const float*)d_in[2];
    const float* w_input  = (const float*)d_in[3];
    const float* b_input  = (const float*)d_in[4];
    const float* w_igate  = (const float*)d_in[5];
    const float* b_igate  = (const float*)d_in[6];
    const float* w_ogate  = (const float*)d_in[7];
    const float* b_ogate  = (const float*)d_in[8];
    const float* h0       = (const float*)d_in[9];
    const float* norm1_w  = (const float*)d_in[10];
    const float* norm2_w  = (const float*)d_in[11];
    const float* w_fc     = (const float*)d_in[12];
    const float* b_fc     = (const float*)d_in[13];
    const float* w_fc_act = (const float*)d_in[14];
    const float* b_fc_act = (const float*)d_in[15];
    const float* w_out    = (const float*)d_in[16];
    const float* b_out    = (const float*)d_in[17];
    float* out = (float*)d_out;   // x1, then final out

    char* ws = (char*)d_ws;
    const size_t MB = 1ull << 20;
    ushort* wtG1  = (ushort*)(ws + 0 * MB);
    ushort* wtG2  = (ushort*)(ws + 4 * MB);
    ushort* wtFC  = (ushort*)(ws + 8 * MB);
    ushort* wtFCA = (ushort*)(ws + 16 * MB);
    ushort* wtOUT = (ushort*)(ws + 24 * MB);
    ushort* xnb   = (ushort*)(ws + 32 * MB);
    ushort* Ga    = (ushort*)(ws + 64 * MB);
    ushort* Gb    = (ushort*)(ws + 96 * MB);
    ushort* Gog   = (ushort*)(ws + 128 * MB);
    ushort* hff   = (ushort*)(ws + 64 * MB);   // [M,4096] bf16, reuses gate region
    float*  P     = (float*)(ws + 192 * MB);
    float*  Hend  = (float*)(ws + 193 * MB);
    float*  Carry = (float*)(ws + 194 * MB);

    // 0) weights -> bf16 [N,K]
    transpose_cast_gates<<<dim3(32, 32, 4), 256, 0, stream>>>(
        w_input, w_forget, w_igate, w_ogate, wtG1, wtG2);
    transpose_cast_kernel<<<dim3(DFF/32, Dd/32), 256, 0, stream>>>(w_fc,     wtFC,  Dd, DFF);
    transpose_cast_kernel<<<dim3(DFF/32, Dd/32), 256, 0, stream>>>(w_fc_act, wtFCA, Dd, DFF);
    transpose_cast_kernel<<<dim3(Dd/32, DFF/32), 256, 0, stream>>>(w_out,    wtOUT, DFF, Dd);

    // 1) xn = rmsnorm(x) -> bf16
    rmsnorm_bf16_kernel<<<Mm, 256, 0, stream>>>(x, norm1_w, xnb);

    // 2) all four gates in one dual-GEMM (N = 2048), 256x128 tiles, 8-phase
    mfma_gemm_gates<<<(2048/128) * (Mm/256), 512, 0, stream>>>(
        xnb, wtG1, wtG2, b_input, b_forget, b_igate, b_ogate, Ga, Gb, Gog);

    // 3) chunked scan + fused ogate/residual + fused rmsnorm2
    dim3 sg(CH, Bb);
    scan_pass1<<<sg, 256, 0, stream>>>(Ga, Gb, P, Hend);
    scan_pass2<<<(Bb * Dd) / 256, 256, 0, stream>>>(P, Hend, h0, Carry);
    scan_pass3_norm<<<sg, 256, 0, stream>>>(Ga, Gb, Gog, Carry, x, norm2_w,
                                            out, xnb);

    // 4) hff = (xn2@w_fc + b) * silu(xn2@w_fc_act + b)  -> bf16 [M,4096]
    mfma_gemm_swiglu<<<(DFF/128) * (Mm/256), 512, 0, stream>>>(
        xnb, wtFC, b_fc, wtFCA, b_fc_act, hff);

    // 5) out = hff @ w_out + b_out + x1   (in-place on d_out)
    mfma_gemm_residual<<<(Dd/256) * (Mm/256), 512, 0, stream>>>(
        hff, wtOUT, b_out, out);
}

// Round 3
// 852.203 us; speedup vs baseline: 1.1672x; 1.0019x over previous
//
#include <hip/hip_runtime.h>
#include <math.h>
#include <stdint.h>

// Problem dims (fixed by reference)
static constexpr int Bb  = 4;
static constexpr int Ll  = 4096;
static constexpr int Dd  = 1024;
static constexpr int DFF = 4096;
static constexpr int Mm  = Bb * Ll;     // 16384 rows
static constexpr int CH  = 64;          // scan chunks
static constexpr int CS  = Ll / CH;     // 64 steps per chunk
static constexpr float EPS = 1e-6f;

typedef __attribute__((ext_vector_type(8))) short short8;     // 8 bf16 (4 VGPRs)
typedef __attribute__((ext_vector_type(4))) float floatx4;    // MFMA C/D
typedef __attribute__((ext_vector_type(4))) unsigned short us4;

__device__ __forceinline__ float sigmoidf_(float v) { return 1.0f / (1.0f + __expf(-v)); }
// safe at +-inf: 2*sigmoid(2x)-1
__device__ __forceinline__ float fast_tanh(float x) {
    return 2.0f / (1.0f + __expf(-2.0f * x)) - 1.0f;
}
__device__ __forceinline__ ushort f2bf(float f) {
    union { float f; uint32_t u; } v; v.f = f;
    return (ushort)((v.u + 0x7FFFu + ((v.u >> 16) & 1u)) >> 16);   // RNE
}
__device__ __forceinline__ float bf2f(ushort h) {
    union { uint32_t u; float f; } v; v.u = (uint32_t)h << 16; return v.f;
}

// async global->LDS, 16 bytes per lane (wave-uniform base + lane*16 layout)
__device__ __forceinline__ void gload16(const ushort* g, ushort* l) {
    __builtin_amdgcn_global_load_lds(
        (const __attribute__((address_space(1))) uint32_t*)g,
        (__attribute__((address_space(3))) uint32_t*)l, 16, 0, 0);
}

// ===========================================================================
// 8-phase pipelined dual-GEMM core (m201 template port), 512 thr / 8 waves.
//   Block tile: 256 rows (A) x 128 cols x 2 outputs (B1,B2 share A).
//   BK = 64 split kk0/kk1; LDS buffer = [Akk0|Akk1|Bkk0|Bkk1], half-tile
//   256x32 bf16 (16 KB contiguous, linear for global_load_lds); 2 buffers.
//   Swizzle (0-conflict proven): chunk (m, s) holds k-block s ^ ((m>>1)&3);
//   read slot = q ^ ((fr>>1)&3).
//   Per K-tile: 4 phases {ds_read 8/4 + stage 1 half-tile -> barrier ->
//   setprio(1) 16 MFMA setprio(0) -> [vmcnt(4) on ph1/ph3] -> barrier}.
//   vmcnt never drains to 0 mid-loop (T4).  In-flight invariant: entering
//   K-tile t exactly {A(t,kk1),B(t,kk1)} (4 loads) outstanding; each
//   vmcnt(4) retires exactly the 2 half-tiles the next 2 phases read.
//   NO sched_barrier(0): the compiler must be free to hoist next-phase
//   ds_read issue / address VALU into the MFMA region (m141 lesson —
//   pinning regressed 880->510 TF; R2 A/B confirmed pinning = no gain).
// ===========================================================================
static constexpr int HT_US  = 256 * 32;       // ushorts per half-tile (16 KB)
static constexpr int BUF_US = 4 * HT_US;      // per buffer (64 KB)

__device__ __forceinline__ void gemm_core_8ph(
    const ushort* __restrict__ A, const ushort* __restrict__ B1,
    const ushort* __restrict__ B2, int m0, int n0b1, int n0b2, int K,
    ushort* lds, floatx4 (&acc1)[8][2], floatx4 (&acc2)[8][2])
{
    const int tid = threadIdx.x;
    const int mm = tid >> 2, ss = tid & 3;
    const int kb = ss ^ ((mm >> 1) & 3);          // swizzled k-slot (staging)
    const ushort* pA0 = A  + (size_t)(m0 + mm) * K + kb * 8;
    const ushort* pA1 = pA0 + (size_t)128 * K;
    const ushort* pB0 = B1 + (size_t)(n0b1 + mm) * K + kb * 8;
    const ushort* pB1 = B2 + (size_t)(n0b2 + mm) * K + kb * 8;

    const int wave = tid >> 6, lane = tid & 63;
    const int wr = wave >> 2, wc = wave & 3;      // 2M x 4N wave grid
    const int fr = lane & 15, q = lane >> 4;
    const int slot8 = (q ^ ((fr >> 1) & 3)) << 3;
    const int aoff  = (wr * 128 + fr) * 32 + slot8;             // + mi*512
    const int boff  = 2 * HT_US + (wc * 32 + fr) * 32 + slot8;  // + ni*512 (+4096 side2)

    const int NT = K >> 6;

#define STG_A(bsel, kk, tt) do { \
        ushort* d_ = lds + (bsel) * BUF_US + (kk) * HT_US; \
        int o_ = (tt) * 64 + (kk) * 32; \
        gload16(pA0 + o_, d_ + tid * 8); \
        gload16(pA1 + o_, d_ + (tid + 512) * 8); } while (0)
#define STG_B(bsel, kk, tt) do { \
        ushort* d_ = lds + (bsel) * BUF_US + (2 + (kk)) * HT_US; \
        int o_ = (tt) * 64 + (kk) * 32; \
        gload16(pB0 + o_, d_ + tid * 8); \
        gload16(pB1 + o_, d_ + (tid + 512) * 8); } while (0)
#define MFMA_HALF(mh) do { \
        __builtin_amdgcn_s_setprio(1); \
        _Pragma("unroll") \
        for (int i_ = 0; i_ < 4; ++i_) { \
            acc1[(mh)*4+i_][0] = __builtin_amdgcn_mfma_f32_16x16x32_bf16(a[i_], b[0], acc1[(mh)*4+i_][0], 0, 0, 0); \
            acc2[(mh)*4+i_][0] = __builtin_amdgcn_mfma_f32_16x16x32_bf16(a[i_], c[0], acc2[(mh)*4+i_][0], 0, 0, 0); \
            acc1[(mh)*4+i_][1] = __builtin_amdgcn_mfma_f32_16x16x32_bf16(a[i_], b[1], acc1[(mh)*4+i_][1], 0, 0, 0); \
            acc2[(mh)*4+i_][1] = __builtin_amdgcn_mfma_f32_16x16x32_bf16(a[i_], c[1], acc2[(mh)*4+i_][1], 0, 0, 0); \
        } \
        __builtin_amdgcn_s_setprio(0); } while (0)

    // ---- prologue: stage K-tile 0; leave its kk1 halves in flight ----
    STG_A(0, 0, 0); STG_B(0, 0, 0); STG_A(0, 1, 0); STG_B(0, 1, 0);
    asm volatile("s_waitcnt vmcnt(4)" ::: "memory");
    __builtin_amdgcn_s_barrier();

    for (int t = 0; t < NT; ++t) {
        const int buf = t & 1, nbuf = buf ^ 1;
        const bool pf = (t + 1 < NT);
        const ushort* Ab = lds + buf * BUF_US;
        short8 a[4], b[2], c[2];

        // ---------- phase 0: kk0, rows mh0 (8 ds_read + stage A kk0) ----------
        #pragma unroll
        for (int i = 0; i < 4; ++i) a[i] = *(const short8*)&Ab[aoff + i * 512];
        #pragma unroll
        for (int n = 0; n < 2; ++n) {
            b[n] = *(const short8*)&Ab[boff + n * 512];
            c[n] = *(const short8*)&Ab[boff + 4096 + n * 512];
        }
        if (pf) STG_A(nbuf, 0, t + 1);
        __builtin_amdgcn_s_barrier();
        MFMA_HALF(0);
        __builtin_amdgcn_s_barrier();

        // ---------- phase 1: kk0, rows mh1 (4 ds_read + stage B kk0) ----------
        #pragma unroll
        for (int i = 0; i < 4; ++i) a[i] = *(const short8*)&Ab[aoff + (i + 4) * 512];
        if (pf) STG_B(nbuf, 0, t + 1);
        __builtin_amdgcn_s_barrier();
        MFMA_HALF(1);
        if (pf) asm volatile("s_waitcnt vmcnt(4)" ::: "memory");
        else    asm volatile("s_waitcnt vmcnt(0)" ::: "memory");
        __builtin_amdgcn_s_barrier();

        // ---------- phase 2: kk1, rows mh0 (8 ds_read + stage A kk1) ----------
        const ushort* Ab1 = Ab + HT_US;
        #pragma unroll
        for (int i = 0; i < 4; ++i) a[i] = *(const short8*)&Ab1[aoff + i * 512];
        #pragma unroll
        for (int n = 0; n < 2; ++n) {
            b[n] = *(const short8*)&Ab1[boff + n * 512];
            c[n] = *(const short8*)&Ab1[boff + 4096 + n * 512];
        }
        if (pf) STG_A(nbuf, 1, t + 1);
        __builtin_amdgcn_s_barrier();
        MFMA_HALF(0);
        __builtin_amdgcn_s_barrier();

        // ---------- phase 3: kk1, rows mh1 (4 ds_read + stage B kk1) ----------
        #pragma unroll
        for (int i = 0; i < 4; ++i) a[i] = *(const short8*)&Ab1[aoff + (i + 4) * 512];
        if (pf) STG_B(nbuf, 1, t + 1);
        __builtin_amdgcn_s_barrier();
        MFMA_HALF(1);
        if (pf) asm volatile("s_waitcnt vmcnt(4)" ::: "memory");
        __builtin_amdgcn_s_barrier();
    }
#undef STG_A
#undef STG_B
#undef MFMA_HALF
}

// ---------------------------------------------------------------------------
// Fused QuasiLSTM gate GEMM (dual, shared A), N = 2048:
//   W1t rows [0,1024) = w_input^T,  [1024,2048) = w_forget^T
//   W2t rows [0,1024) = w_igate^T,  [1024,2048) = w_ogate^T
// col <  1024:  Gb  = tanh(z1) * sigmoid(z2)
// col >= 1024:  Ga  = sigmoid(z1);  Gog = sigmoid(z2)
// ---------------------------------------------------------------------------
__global__ __launch_bounds__(512) void mfma_gemm_gates(
    const ushort* __restrict__ A, const ushort* __restrict__ W1t,
    const ushort* __restrict__ W2t,
    const float* __restrict__ b_input, const float* __restrict__ b_forget,
    const float* __restrict__ b_igate, const float* __restrict__ b_ogate,
    ushort* __restrict__ Ga, ushort* __restrict__ Gb, ushort* __restrict__ Gog)
{
    __shared__ __align__(16) ushort lds[2 * BUF_US];
    // XCD-slice swizzle: each XCD owns 2 bx columns (B-slice 1MB, L2-resident)
    int xcd = blockIdx.x & 7, i = blockIdx.x >> 3;   // i in [0,128)
    int bx = xcd * 2 + (i & 1), by = i >> 1;
    int m0 = by * 256, n0 = bx * 128;

    floatx4 acc1[8][2] = {};
    floatx4 acc2[8][2] = {};
    gemm_core_8ph(A, W1t, W2t, m0, n0, n0, Dd, lds, acc1, acc2);

    int tid = threadIdx.x, wave = tid >> 6, lane = tid & 63;
    int wr = wave >> 2, wc = wave & 3, fr = lane & 15, q = lane >> 4;
    #pragma unroll
    for (int ni = 0; ni < 2; ++ni) {
        int col = n0 + wc * 32 + ni * 16 + fr;        // [0,2048)
        if (col < 1024) {
            float b1v = b_input[col], b2v = b_igate[col];
            #pragma unroll
            for (int mi = 0; mi < 8; ++mi)
                #pragma unroll
                for (int r = 0; r < 4; ++r) {
                    int row = m0 + wr * 128 + mi * 16 + q * 4 + r;
                    float z1 = acc1[mi][ni][r] + b1v;
                    float z2 = acc2[mi][ni][r] + b2v;
                    Gb[(size_t)row * Dd + col] = f2bf(fast_tanh(z1) * sigmoidf_(z2));
                }
        } else {
            int c2 = col - 1024;
            float b1v = b_forget[c2], b2v = b_ogate[c2];
            #pragma unroll
            for (int mi = 0; mi < 8; ++mi)
                #pragma unroll
                for (int r = 0; r < 4; ++r) {
                    int row = m0 + wr * 128 + mi * 16 + q * 4 + r;
                    float z1 = acc1[mi][ni][r] + b1v;
                    float z2 = acc2[mi][ni][r] + b2v;
                    Ga[(size_t)row * Dd + c2]  = f2bf(sigmoidf_(z1));
                    Gog[(size_t)row * Dd + c2] = f2bf(sigmoidf_(z2));
                }
        }
    }
}

// ---------------------------------------------------------------------------
// MFMA dual GEMM for SwiGLU: C = (A@W1+b1) * silu(A@W2+b2), bf16 out
// ---------------------------------------------------------------------------
__global__ __launch_bounds__(512) void mfma_gemm_swiglu(
    const ushort* __restrict__ A, const ushort* __restrict__ W1t,
    const float* __restrict__ b1, const ushort* __restrict__ W2t,
    const float* __restrict__ b2, ushort* __restrict__ C)
{
    __shared__ __align__(16) ushort lds[2 * BUF_US];
    // XCD-slice swizzle: each XCD owns 4 bx columns (B-slice 2MB, L2-resident)
    int xcd = blockIdx.x & 7, i = blockIdx.x >> 3;   // i in [0,256)
    int bx = xcd * 4 + (i & 3), by = i >> 2;
    int m0 = by * 256, n0 = bx * 128;

    floatx4 acc1[8][2] = {};
    floatx4 acc2[8][2] = {};
    gemm_core_8ph(A, W1t, W2t, m0, n0, n0, Dd, lds, acc1, acc2);

    int tid = threadIdx.x, wave = tid >> 6, lane = tid & 63;
    int wr = wave >> 2, wc = wave & 3, fr = lane & 15, q = lane >> 4;
    #pragma unroll
    for (int ni = 0; ni < 2; ++ni) {
        int col = n0 + wc * 32 + ni * 16 + fr;
        float b1v = b1[col], b2v = b2[col];
        #pragma unroll
        for (int mi = 0; mi < 8; ++mi)
            #pragma unroll
            for (int r = 0; r < 4; ++r) {
                int row = m0 + wr * 128 + mi * 16 + q * 4 + r;
                float z1 = acc1[mi][ni][r] + b1v;
                float z2 = acc2[mi][ni][r] + b2v;
                C[(size_t)row * DFF + col] = f2bf(z1 * z2 * sigmoidf_(z2));
            }
    }
}

// ---------------------------------------------------------------------------
// MFMA residual GEMM: out_f32 = A_bf16[M,K] @ Wt[N,K]^T + bias + R (R == out)
// Single-B: the 256-wide N tile is two 128 halves (acc1/acc2).
// ---------------------------------------------------------------------------
__global__ __launch_bounds__(512) void mfma_gemm_residual(
    const ushort* __restrict__ A, const ushort* __restrict__ Wt,
    const float* __restrict__ bias, float* __restrict__ C)
{
    __shared__ __align__(16) ushort lds[2 * BUF_US];
    int xcd = blockIdx.x & 7, i = blockIdx.x >> 3;   // i in [0,32)
    int s = xcd * 32 + i;
    int bx = s & 3, by = s >> 2;                     // bx fast: A-panel reuse
    int m0 = by * 256, n0 = bx * 256;

    floatx4 acc1[8][2] = {};
    floatx4 acc2[8][2] = {};
    gemm_core_8ph(A, Wt, Wt, m0, n0, n0 + 128, DFF, lds, acc1, acc2);

    int tid = threadIdx.x, wave = tid >> 6, lane = tid & 63;
    int wr = wave >> 2, wc = wave & 3, fr = lane & 15, q = lane >> 4;
    #pragma unroll
    for (int ni = 0; ni < 2; ++ni) {
        int col1 = n0 + wc * 32 + ni * 16 + fr;
        int col2 = col1 + 128;
        float bs1 = bias[col1], bs2 = bias[col2];
        #pragma unroll
        for (int mi = 0; mi < 8; ++mi)
            #pragma unroll
            for (int r = 0; r < 4; ++r) {
                int row = m0 + wr * 128 + mi * 16 + q * 4 + r;
                size_t i1 = (size_t)row * Dd + col1;
                size_t i2 = (size_t)row * Dd + col2;
                C[i1] = acc1[mi][ni][r] + bs1 + C[i1];  // same-thread RMW
                C[i2] = acc2[mi][ni][r] + bs2 + C[i2];
            }
    }
}

// ---------------------------------------------------------------------------
// Weight cast+transpose: W fp32 [K,N] -> Wt bf16 [N,K]
// ---------------------------------------------------------------------------
__global__ __launch_bounds__(256) void transpose_cast_kernel(
    const float* __restrict__ W, ushort* __restrict__ Wt, int K, int N)
{
    __shared__ float t[32][33];
    int lx = threadIdx.x & 31, ly = threadIdx.x >> 5;   // 32 x 8
    int n = blockIdx.x * 32 + lx;
    #pragma unroll
    for (int i = 0; i < 4; ++i) {
        int k = blockIdx.y * 32 + ly + i * 8;
        t[ly + i * 8][lx] = W[(size_t)k * N + n];
    }
    __syncthreads();
    int k2 = blockIdx.y * 32 + lx;
    #pragma unroll
    for (int i = 0; i < 4; ++i) {
        int n2 = blockIdx.x * 32 + ly + i * 8;
        Wt[(size_t)n2 * K + k2] = f2bf(t[lx][ly + i * 8]);
    }
}

// Batched version for the four 1024x1024 gate weights (grid.z picks source).
__global__ __launch_bounds__(256) void transpose_cast_gates(
    const float* __restrict__ w_i, const float* __restrict__ w_f,
    const float* __restrict__ w_g, const float* __restrict__ w_o,
    ushort* __restrict__ W1t, ushort* __restrict__ W2t)
{
    int z = blockIdx.z;
    const float* W = (z == 0) ? w_i : (z == 1) ? w_f : (z == 2) ? w_g : w_o;
    ushort* Wt = (z == 0) ? W1t : (z == 1) ? W1t + (size_t)1024 * Dd
               : (z == 2) ? W2t : W2t + (size_t)1024 * Dd;
    __shared__ float t[32][33];
    int lx = threadIdx.x & 31, ly = threadIdx.x >> 5;
    int n = blockIdx.x * 32 + lx;
    #pragma unroll
    for (int i = 0; i < 4; ++i) {
        int k = blockIdx.y * 32 + ly + i * 8;
        t[ly + i * 8][lx] = W[(size_t)k * Dd + n];
    }
    __syncthreads();
    int k2 = blockIdx.y * 32 + lx;
    #pragma unroll
    for (int i = 0; i < 4; ++i) {
        int n2 = blockIdx.x * 32 + ly + i * 8;
        Wt[(size_t)n2 * Dd + k2] = f2bf(t[lx][ly + i * 8]);
    }
}

// ---------------------------------------------------------------------------
// RMSNorm fp32 in -> bf16 out. One block per row.
// ---------------------------------------------------------------------------
__global__ __launch_bounds__(256) void rmsnorm_bf16_kernel(
    const float* __restrict__ x, const float* __restrict__ w,
    ushort* __restrict__ o)
{
    int row = blockIdx.x;
    int tid = threadIdx.x;
    float4 v = ((const float4*)(x + (size_t)row * Dd))[tid];
    float ss = v.x*v.x + v.y*v.y + v.z*v.z + v.w*v.w;
    #pragma unroll
    for (int off = 32; off > 0; off >>= 1) ss += __shfl_down(ss, off, 64);
    __shared__ float red[4];
    if ((tid & 63) == 0) red[tid >> 6] = ss;
    __syncthreads();
    float scale = rsqrtf((red[0] + red[1] + red[2] + red[3]) * (1.0f / Dd) + EPS);
    float4 wv = ((const float4*)w)[tid];
    us4 ov;
    ov.x = f2bf(v.x * scale * wv.x);
    ov.y = f2bf(v.y * scale * wv.y);
    ov.z = f2bf(v.z * scale * wv.z);
    ov.w = f2bf(v.w * scale * wv.w);
    *(us4*)&o[(size_t)row * Dd + tid * 4] = ov;
}

// ---------------------------------------------------------------------------
// Chunked linear recurrence, 4 channels/thread (ushort4 loads)
// ---------------------------------------------------------------------------
__global__ __launch_bounds__(256) void scan_pass1(
    const ushort* __restrict__ Ga, const ushort* __restrict__ Gb,
    float* __restrict__ P, float* __restrict__ Hend)
{
    int tid = threadIdx.x;
    int c = blockIdx.x, b = blockIdx.y;
    size_t base = ((size_t)b * Ll + (size_t)c * CS) * Dd + tid * 4;
    float p[4] = {1.f, 1.f, 1.f, 1.f};
    float h[4] = {};
    #pragma unroll 4
    for (int t = 0; t < CS; ++t) {
        us4 av = *(const us4*)&Ga[base + (size_t)t * Dd];
        us4 bv = *(const us4*)&Gb[base + (size_t)t * Dd];
        #pragma unroll
        for (int j = 0; j < 4; ++j) {
            float aa = bf2f(av[j]);
            float bb = bf2f(bv[j]);
            p[j] *= aa;
            h[j] = aa * h[j] + bb;
        }
    }
    size_t o = ((size_t)b * CH + c) * Dd + tid * 4;
    *(float4*)&P[o]    = make_float4(p[0], p[1], p[2], p[3]);
    *(float4*)&Hend[o] = make_float4(h[0], h[1], h[2], h[3]);
}

__global__ __launch_bounds__(256) void scan_pass2(
    const float* __restrict__ P, const float* __restrict__ Hend,
    const float* __restrict__ h0, float* __restrict__ Carry)
{
    int idx = blockIdx.x * 256 + threadIdx.x;  // B*D = 4096
    int b = idx / Dd, d = idx % Dd;
    float carry = h0[d];
    for (int c = 0; c < CH; ++c) {
        size_t o = ((size_t)b * CH + c) * Dd + d;
        Carry[o] = carry;
        carry = P[o] * carry + Hend[o];
    }
}

// Replay with carry + fused ogate/residual + fused RMSNorm2
__global__ __launch_bounds__(256) void scan_pass3_norm(
    const ushort* __restrict__ Ga, const ushort* __restrict__ Gb,
    const ushort* __restrict__ Gog, const float* __restrict__ Carry,
    const float* __restrict__ x, const float* __restrict__ norm2w,
    float* __restrict__ x1, ushort* __restrict__ xnb)
{
    int tid = threadIdx.x;
    int c = blockIdx.x, b = blockIdx.y;
    size_t base = ((size_t)b * Ll + (size_t)c * CS) * Dd + tid * 4;
    float4 h4 = *(const float4*)&Carry[((size_t)b * CH + c) * Dd + tid * 4];
    float h[4] = {h4.x, h4.y, h4.z, h4.w};
    float4 w4 = ((const float4*)norm2w)[tid];
    float wv[4] = {w4.x, w4.y, w4.z, w4.w};
    __shared__ float red[4];

    for (int t = 0; t < CS; ++t) {
        size_t i = base + (size_t)t * Dd;
        us4 av = *(const us4*)&Ga[i];
        us4 bv = *(const us4*)&Gb[i];
        us4 gv = *(const us4*)&Gog[i];
        float4 xv = *(const float4*)&x[i];
        float xs[4] = {xv.x, xv.y, xv.z, xv.w};
        float v[4];
        #pragma unroll
        for (int j = 0; j < 4; ++j) {
            float aa = bf2f(av[j]);
            float bb = bf2f(bv[j]);
            h[j] = aa * h[j] + bb;
            v[j] = fast_tanh(h[j]) * bf2f(gv[j]) + xs[j];
        }
        *(float4*)&x1[i] = make_float4(v[0], v[1], v[2], v[3]);
        float ss = v[0]*v[0] + v[1]*v[1] + v[2]*v[2] + v[3]*v[3];
        #pragma unroll
        for (int off = 32; off > 0; off >>= 1) ss += __shfl_down(ss, off, 64);
        if ((tid & 63) == 0) red[tid >> 6] = ss;
        __syncthreads();
        float scale = rsqrtf((red[0] + red[1] + red[2] + red[3]) * (1.0f / Dd) + EPS);
        us4 ov;
        #pragma unroll
        for (int j = 0; j < 4; ++j) ov[j] = f2bf(v[j] * scale * wv[j]);
        *(us4*)&xnb[i] = ov;
        __syncthreads();   // protect red[] before next t overwrites
    }
}

// ---------------------------------------------------------------------------
// Launch. Workspace (195 MB):
//   [0,4)   MB: W1t gates bf16 [2048,1024]   (input | forget)
//   [4,8)   MB: W2t gates bf16 [2048,1024]   (igate | ogate)
//   [8,16)  MB: wtFC   [16,24) MB: wtFCA   [24,32) MB: wtOUT
//   [32,64) MB: xnb bf16 [M,1024]
//   [64,192)MB: Ga/Gb/Gog bf16 (32MB each) -> later hff bf16 [M,4096]
//   [192,195)MB: P, Hend, Carry fp32
// d_out doubles as x1 then final out.
// ---------------------------------------------------------------------------
extern "C" void kernel_launch(void* const* d_in, const int* in_sizes, int n_in,
                              void* d_out, int out_size, void* d_ws, size_t ws_size,
                              hipStream_t stream)
{
    const float* x        = (const float*)d_in[0];
    const float* w_forget = (const float*)d_in[1];
    const float* b_forget = (const float*)d_in[2];
    const float* w_input  = (const float*)d_in[3];
    const float* b_input  = (const float*)d_in[4];
    const float* w_igate  = (const float*)d_in[5];
    const float* b_igate  = (const float*)d_in[6];
    const float* w_ogate  = (const float*)d_in[7];
    const float* b_ogate  = (const float*)d_in[8];
    const float* h0       = (const float*)d_in[9];
    const float* norm1_w  = (const float*)d_in[10];
    const float* norm2_w  = (const float*)d_in[11];
    const float* w_fc     = (const float*)d_in[12];
    const float* b_fc     = (const float*)d_in[13];
    const float* w_fc_act = (const float*)d_in[14];
    const float* b_fc_act = (const float*)d_in[15];
    const float* w_out    = (const float*)d_in[16];
    const float* b_out    = (const float*)d_in[17];
    float* out = (float*)d_out;   // x1, then final out

    char* ws = (char*)d_ws;
    const size_t MB = 1ull << 20;
    ushort* wtG1  = (ushort*)(ws + 0 * MB);
    ushort* wtG2  = (ushort*)(ws + 4 * MB);
    ushort* wtFC  = (ushort*)(ws + 8 * MB);
    ushort* wtFCA = (ushort*)(ws + 16 * MB);
    ushort* wtOUT = (ushort*)(ws + 24 * MB);
    ushort* xnb   = (ushort*)(ws + 32 * MB);
    ushort* Ga    = (ushort*)(ws + 64 * MB);
    ushort* Gb    = (ushort*)(ws + 96 * MB);
    ushort* Gog   = (ushort*)(ws + 128 * MB);
    ushort* hff   = (ushort*)(ws + 64 * MB);   // [M,4096] bf16, reuses gate region
    float*  P     = (float*)(ws + 192 * MB);
    float*  Hend  = (float*)(ws + 193 * MB);
    float*  Carry = (float*)(ws + 194 * MB);

    // 0) weights -> bf16 [N,K]
    transpose_cast_gates<<<dim3(32, 32, 4), 256, 0, stream>>>(
        w_input, w_forget, w_igate, w_ogate, wtG1, wtG2);
    transpose_cast_kernel<<<dim3(DFF/32, Dd/32), 256, 0, stream>>>(w_fc,     wtFC,  Dd, DFF);
    transpose_cast_kernel<<<dim3(DFF/32, Dd/32), 256, 0, stream>>>(w_fc_act, wtFCA, Dd, DFF);
    transpose_cast_kernel<<<dim3(Dd/32, DFF/32), 256, 0, stream>>>(w_out,    wtOUT, DFF, Dd);

    // 1) xn = rmsnorm(x) -> bf16
    rmsnorm_bf16_kernel<<<Mm, 256, 0, stream>>>(x, norm1_w, xnb);

    // 2) all four gates in one dual-GEMM (N = 2048), 256x128 tiles, 8-phase
    mfma_gemm_gates<<<(2048/128) * (Mm/256), 512, 0, stream>>>(
        xnb, wtG1, wtG2, b_input, b_forget, b_igate, b_ogate, Ga, Gb, Gog);

    // 3) chunked scan + fused ogate/residual + fused rmsnorm2
    dim3 sg(CH, Bb);
    scan_pass1<<<sg, 256, 0, stream>>>(Ga, Gb, P, Hend);
    scan_pass2<<<(Bb * Dd) / 256, 256, 0, stream>>>(P, Hend, h0, Carry);
    scan_pass3_norm<<<sg, 256, 0, stream>>>(Ga, Gb, Gog, Carry, x, norm2_w,
                                            out, xnb);

    // 4) hff = (xn2@w_fc + b) * silu(xn2@w_fc_act + b)  -> bf16 [M,4096]
    mfma_gemm_swiglu<<<(DFF/128) * (Mm/256), 512, 0, stream>>>(
        xnb, wtFC, b_fc, wtFCA, b_fc_act, hff);

    // 5) out = hff @ w_out + b_out + x1   (in-place on d_out)
    mfma_gemm_residual<<<(Dd/256) * (Mm/256), 512, 0, stream>>>(
        hff, wtOUT, b_out, out);
}